// Round 1
// baseline (1512.243 us; speedup 1.0000x reference)
//
#include <hip/hip_runtime.h>

#define BB 32
#define TT 2048
#define DD 64
#define PRED 96
#define TP (TT + PRED)      // 2144
#define KTOP 8
#define NSIG (BB * DD)      // 2048

// ---------------------------------------------------------------------------
// Kernel B: per-signal DFT (bins 1..1023) + fp64-accurate top-8 selection.
// One block per signal s = b*64 + d. 256 threads, 4 bins per thread.
// Accuracy note: top-k gaps can be ~1e-5 relative; fp64 accumulation keeps our
// magnitude error ~1e-8 relative so selection matches the reference.
// ---------------------------------------------------------------------------
__global__ __launch_bounds__(256) void dft_topk_kernel(const float* __restrict__ x,
                                                       int* __restrict__ idxw,
                                                       float* __restrict__ rew,
                                                       float* __restrict__ imw) {
    __shared__ float  xs[TT];
    __shared__ double sRe[TT / 2 + 1];   // index by bin k, slots 0..1024
    __shared__ double sIm[TT / 2 + 1];
    __shared__ double sMag[TT / 2 + 1];
    __shared__ double bv[256];
    __shared__ int    bi[256];
    __shared__ int    wins[KTOP];

    const int s   = blockIdx.x;
    const int b   = s >> 6;
    const int d   = s & 63;
    const int tid = threadIdx.x;

    // Stage signal x[b, :, d] into LDS (strided global reads, L2-served).
    for (int n = tid; n < TT; n += 256) {
        xs[n] = x[((size_t)b * TT + n) * DD + d];
    }
    if (tid == 0) sMag[0] = -1.0;  // DC excluded (LOW_FREQ=1)
    __syncthreads();

    // Bins k = 4*tid+1 .. 4*tid+4  (k=1024 computed but invalidated: Nyquist excluded)
    const int k0 = 4 * tid + 1;
    double aRe[4] = {0.0, 0.0, 0.0, 0.0};
    double aIm[4] = {0.0, 0.0, 0.0, 0.0};
    int j[4] = {0, 0, 0, 0};           // j = (k*n) mod 2048, exact reduction
    const float invT = 1.0f / (float)TT;

    for (int n = 0; n < TT; ++n) {
        const float xn = xs[n];        // same address all lanes -> LDS broadcast
        #pragma unroll
        for (int p = 0; p < 4; ++p) {
            const float rev = (float)j[p] * invT;          // exact: j/2048
            const float c  = __builtin_amdgcn_cosf(rev);   // cos(2*pi*rev)
            const float sn = __builtin_amdgcn_sinf(rev);   // sin(2*pi*rev)
            aRe[p] += (double)(xn * c);
            aIm[p] -= (double)(xn * sn);
            j[p] = (j[p] + (k0 + p)) & (TT - 1);
        }
    }

    #pragma unroll
    for (int p = 0; p < 4; ++p) {
        const int k = k0 + p;          // 1..1024
        sRe[k]  = aRe[p];
        sIm[k]  = aIm[p];
        sMag[k] = (k <= TT / 2 - 1) ? (aRe[p] * aRe[p] + aIm[p] * aIm[p]) : -1.0;
    }
    __syncthreads();

    // 8 argmax passes; tie -> lowest bin index (matches lax.top_k stability).
    for (int pass = 0; pass < KTOP; ++pass) {
        double best = -2.0;
        int    bidx = 1 << 30;
        #pragma unroll
        for (int p = 0; p < 4; ++p) {
            const int k = k0 + p;
            const double v = sMag[k];
            if (v > best || (v == best && k < bidx)) { best = v; bidx = k; }
        }
        bv[tid] = best;
        bi[tid] = bidx;
        __syncthreads();
        for (int s2 = 128; s2 > 0; s2 >>= 1) {
            if (tid < s2) {
                const double v2 = bv[tid + s2];
                const int    i2 = bi[tid + s2];
                if (v2 > bv[tid] || (v2 == bv[tid] && i2 < bi[tid])) {
                    bv[tid] = v2; bi[tid] = i2;
                }
            }
            __syncthreads();
        }
        if (tid == 0) {
            const int w = bi[0];
            wins[pass] = w;
            sMag[w] = -1.0;            // exclude from later passes
        }
        __syncthreads();
    }

    if (tid < KTOP) {
        const int k = wins[tid];
        idxw[s * KTOP + tid] = k;
        // fold the (2/T) factor (pair + conjugate-pair collapse) here
        rew[s * KTOP + tid] = (float)(sRe[k] * (2.0 / (double)TT));
        imw[s * KTOP + tid] = (float)(sIm[k] * (2.0 / (double)TT));
    }
}

// ---------------------------------------------------------------------------
// Kernel C: synthesis. out[b,t,d] = sum_p rew*cos(2*pi*k*t/T) - imw*sin(...)
// Block = (b, 128-wide t-tile); lanes are d-major -> coalesced stores.
// ---------------------------------------------------------------------------
__global__ __launch_bounds__(256) void synth_kernel(const int* __restrict__ idxw,
                                                    const float* __restrict__ rew,
                                                    const float* __restrict__ imw,
                                                    float* __restrict__ out) {
    const int NT   = (TP + 127) / 128;   // 17 tiles
    const int b    = blockIdx.x / NT;
    const int tile = blockIdx.x % NT;
    const int tid  = threadIdx.x;
    const int d    = tid & 63;
    const int tq   = tid >> 6;           // 0..3
    const int s    = b * DD + d;

    int   kk[KTOP];
    float rr[KTOP], ii[KTOP];
    int   jj[KTOP];
    #pragma unroll
    for (int p = 0; p < KTOP; ++p) {
        kk[p] = idxw[s * KTOP + p];
        rr[p] = rew[s * KTOP + p];
        ii[p] = imw[s * KTOP + p];
    }
    const int t0 = tile * 128 + tq * 32;
    #pragma unroll
    for (int p = 0; p < KTOP; ++p) jj[p] = (kk[p] * t0) & (TT - 1);

    const float invT = 1.0f / (float)TT;
    for (int i = 0; i < 32; ++i) {
        const int t = t0 + i;
        if (t < TP) {
            float acc = 0.0f;
            #pragma unroll
            for (int p = 0; p < KTOP; ++p) {
                const float rev = (float)jj[p] * invT;
                const float c  = __builtin_amdgcn_cosf(rev);
                const float sn = __builtin_amdgcn_sinf(rev);
                acc += rr[p] * c - ii[p] * sn;
            }
            out[((size_t)b * TP + t) * DD + d] = acc;
        }
        #pragma unroll
        for (int p = 0; p < KTOP; ++p) jj[p] = (jj[p] + kk[p]) & (TT - 1);
    }
}

extern "C" void kernel_launch(void* const* d_in, const int* in_sizes, int n_in,
                              void* d_out, int out_size, void* d_ws, size_t ws_size,
                              hipStream_t stream) {
    const float* x = (const float*)d_in[0];
    float* out = (float*)d_out;

    int*   idxw = (int*)d_ws;
    float* rew  = (float*)((char*)d_ws + (size_t)NSIG * KTOP * sizeof(int));
    float* imw  = rew + (size_t)NSIG * KTOP;

    dft_topk_kernel<<<NSIG, 256, 0, stream>>>(x, idxw, rew, imw);

    const int NT = (TP + 127) / 128;
    synth_kernel<<<BB * NT, 256, 0, stream>>>(idxw, rew, imw, out);
}

// Round 2
// 145.974 us; speedup vs baseline: 10.3597x; 10.3597x over previous
//
#include <hip/hip_runtime.h>

#define BB 32
#define TT 2048
#define DD 64
#define PRED 96
#define TP (TT + PRED)      // 2144
#define KTOP 8
#define NSIG (BB * DD)      // 2048
#define LOG2T 11

// ---------------------------------------------------------------------------
// Twiddle table: twid[j] = exp(-2*pi*i*j/2048), j = 0..1023, fp64.
// Recomputed every launch (d_ws is re-poisoned before each timed call).
// ---------------------------------------------------------------------------
__global__ void twiddle_kernel(double2* __restrict__ twid) {
    const int j = blockIdx.x * 256 + threadIdx.x;
    if (j < TT / 2) {
        const double th = -2.0 * 3.14159265358979323846 * (double)j / (double)TT;
        twid[j] = make_double2(cos(th), sin(th));
    }
}

// ---------------------------------------------------------------------------
// Kernel B: packed complex FFT (2 real channels per block) + fp64 top-8.
// Block = (b, d-pair). 1024 blocks x 256 threads. LDS: 32 KB (re+im fp64).
// x1 = x[b,:,2*dp], x2 = x[b,:,2*dp+1] -> z = x1 + i*x2, one 2048-pt FFT,
// unpack: X1[k] = (Z[k]+conj(Z[N-k]))/2, X2[k] = -i*(Z[k]-conj(Z[N-k]))/2.
// fp64 keeps per-bin error ~1e-13 rel, far below the min top-k gap (~1e-5).
// ---------------------------------------------------------------------------
__global__ __launch_bounds__(256) void fft_topk_kernel(const float* __restrict__ x,
                                                       const double2* __restrict__ twid,
                                                       int* __restrict__ idxw,
                                                       float* __restrict__ rew,
                                                       float* __restrict__ imw) {
    __shared__ double re[TT];
    __shared__ double im[TT];
    __shared__ double bv[4];
    __shared__ int    bi[4];
    __shared__ int    wins[2 * KTOP];

    const int blk = blockIdx.x;        // 0..1023
    const int b   = blk >> 5;          // batch
    const int dp  = blk & 31;          // d-pair: channels 2*dp, 2*dp+1
    const int tid = threadIdx.x;

    // Stage input in bit-reversed order. float2 pulls both channels at once.
    const float2* x2v = (const float2*)x;   // index (b*2048+n)*32 + dp
    #pragma unroll
    for (int q = 0; q < 8; ++q) {
        const int n = tid + 256 * q;
        const float2 v = x2v[((size_t)b * TT + n) * (DD / 2) + dp];
        const int r = __brev((unsigned)n) >> (32 - LOG2T);
        re[r] = (double)v.x;
        im[r] = (double)v.y;
    }
    __syncthreads();

    // 11 radix-2 DIT stages; 1024 butterflies/stage, 4 per thread.
    for (int s = 1; s <= LOG2T; ++s) {
        const int half = 1 << (s - 1);
        const int twsh = LOG2T - s;
        #pragma unroll 2
        for (int q = 0; q < 4; ++q) {
            const int bf = tid + 256 * q;
            const int j  = bf & (half - 1);
            const int g  = bf >> (s - 1);
            const int i0 = (g << s) + j;
            const int i1 = i0 + half;
            const double2 w = twid[j << twsh];
            const double ar = re[i0], ai = im[i0];
            const double br = re[i1], bq = im[i1];
            const double tr = br * w.x - bq * w.y;
            const double ti = br * w.y + bq * w.x;
            re[i0] = ar + tr; im[i0] = ai + ti;
            re[i1] = ar - tr; im[i1] = ai - ti;
        }
        __syncthreads();
    }

    // Per-thread magnitudes for bins k = 4*tid+1 .. 4*tid+4 (k=1024 excluded).
    double mg[8];
    #pragma unroll
    for (int p = 0; p < 4; ++p) {
        const int k = 4 * tid + 1 + p;
        if (k <= TT / 2 - 1) {
            const double zr = re[k],      zi = im[k];
            const double yr = re[TT - k], yi = im[TT - k];
            const double x1r = 0.5 * (zr + yr), x1i = 0.5 * (zi - yi);
            const double x2r = 0.5 * (zi + yi), x2i = 0.5 * (yr - zr);
            mg[p]     = x1r * x1r + x1i * x1i;
            mg[4 + p] = x2r * x2r + x2i * x2i;
        } else {
            mg[p] = -1.0; mg[4 + p] = -1.0;
        }
    }

    // Top-8 per signal: wave shuffle argmax + 4-wave combine; ties -> low k.
    const int lane = tid & 63;
    const int wv   = tid >> 6;
    for (int sig = 0; sig < 2; ++sig) {
        for (int pass = 0; pass < KTOP; ++pass) {
            double best = -2.0;
            int    bidx = 1 << 30;
            #pragma unroll
            for (int p = 0; p < 4; ++p) {
                const double v = mg[sig * 4 + p];
                if (v > best) { best = v; bidx = 4 * tid + 1 + p; }
            }
            #pragma unroll
            for (int off = 32; off; off >>= 1) {
                const double ov = __shfl_xor(best, off, 64);
                const int    oi = __shfl_xor(bidx, off, 64);
                if (ov > best || (ov == best && oi < bidx)) { best = ov; bidx = oi; }
            }
            if (lane == 0) { bv[wv] = best; bi[wv] = bidx; }
            __syncthreads();
            double fb = bv[0]; int fi = bi[0];
            #pragma unroll
            for (int w2 = 1; w2 < 4; ++w2) {
                if (bv[w2] > fb || (bv[w2] == fb && bi[w2] < fi)) { fb = bv[w2]; fi = bi[w2]; }
            }
            if (((fi - 1) >> 2) == tid) mg[sig * 4 + ((fi - 1) & 3)] = -1.0;  // exclude winner
            if (tid == 0) wins[sig * KTOP + pass] = fi;
            __syncthreads();
        }
    }

    // Unpack + write the 16 winning coefficients (2/T factor folded in).
    if (tid < 2 * KTOP) {
        const int sig = tid >> 3;
        const int r   = tid & 7;
        const int k   = wins[sig * KTOP + r];
        const double zr = re[k],      zi = im[k];
        const double yr = re[TT - k], yi = im[TT - k];
        double cr, ci;
        if (sig == 0) { cr = 0.5 * (zr + yr); ci = 0.5 * (zi - yi); }
        else          { cr = 0.5 * (zi + yi); ci = 0.5 * (yr - zr); }
        const int sidx = (b * DD + 2 * dp + sig) * KTOP + r;
        idxw[sidx] = k;
        rew[sidx]  = (float)(cr * (2.0 / (double)TT));
        imw[sidx]  = (float)(ci * (2.0 / (double)TT));
    }
}

// ---------------------------------------------------------------------------
// Kernel C: synthesis (unchanged from R0 — passed). Lanes d-major, coalesced.
// out[b,t,d] = sum_p rew*cos(2*pi*k*t/T) - imw*sin(2*pi*k*t/T); exact integer
// angle reduction j = (k*t) mod 2048, HW trig in revolutions.
// ---------------------------------------------------------------------------
__global__ __launch_bounds__(256) void synth_kernel(const int* __restrict__ idxw,
                                                    const float* __restrict__ rew,
                                                    const float* __restrict__ imw,
                                                    float* __restrict__ out) {
    const int NT   = (TP + 127) / 128;   // 17 tiles
    const int b    = blockIdx.x / NT;
    const int tile = blockIdx.x % NT;
    const int tid  = threadIdx.x;
    const int d    = tid & 63;
    const int tq   = tid >> 6;           // 0..3
    const int s    = b * DD + d;

    int   kk[KTOP];
    float rr[KTOP], ii[KTOP];
    int   jj[KTOP];
    #pragma unroll
    for (int p = 0; p < KTOP; ++p) {
        kk[p] = idxw[s * KTOP + p];
        rr[p] = rew[s * KTOP + p];
        ii[p] = imw[s * KTOP + p];
    }
    const int t0 = tile * 128 + tq * 32;
    #pragma unroll
    for (int p = 0; p < KTOP; ++p) jj[p] = (kk[p] * t0) & (TT - 1);

    const float invT = 1.0f / (float)TT;
    for (int i = 0; i < 32; ++i) {
        const int t = t0 + i;
        if (t < TP) {
            float acc = 0.0f;
            #pragma unroll
            for (int p = 0; p < KTOP; ++p) {
                const float rev = (float)jj[p] * invT;
                const float c  = __builtin_amdgcn_cosf(rev);
                const float sn = __builtin_amdgcn_sinf(rev);
                acc += rr[p] * c - ii[p] * sn;
            }
            out[((size_t)b * TP + t) * DD + d] = acc;
        }
        #pragma unroll
        for (int p = 0; p < KTOP; ++p) jj[p] = (jj[p] + kk[p]) & (TT - 1);
    }
}

extern "C" void kernel_launch(void* const* d_in, const int* in_sizes, int n_in,
                              void* d_out, int out_size, void* d_ws, size_t ws_size,
                              hipStream_t stream) {
    const float* x = (const float*)d_in[0];
    float* out = (float*)d_out;

    // ws layout: twid (16 KB, double2-aligned at 0) | idxw | rew | imw
    double2* twid = (double2*)d_ws;
    char* p = (char*)d_ws + (size_t)(TT / 2) * sizeof(double2);
    int*   idxw = (int*)p;
    float* rew  = (float*)(p + (size_t)NSIG * KTOP * sizeof(int));
    float* imw  = rew + (size_t)NSIG * KTOP;

    twiddle_kernel<<<(TT / 2 + 255) / 256, 256, 0, stream>>>(twid);
    fft_topk_kernel<<<NSIG / 2, 256, 0, stream>>>(x, twid, idxw, rew, imw);

    const int NT = (TP + 127) / 128;
    synth_kernel<<<BB * NT, 256, 0, stream>>>(idxw, rew, imw, out);
}

// Round 3
// 121.536 us; speedup vs baseline: 12.4427x; 1.2011x over previous
//
#include <hip/hip_runtime.h>

#define BB 32
#define TT 2048
#define DD 64
#define PRED 96
#define TP (TT + PRED)      // 2144
#define KTOP 8
#define NCAND 12
#define NSIG (BB * DD)      // 2048
#define MARGIN 2e-4f
#define PI_D 3.14159265358979323846

// LDS bank swizzle for the float2 FFT array: phys = idx ^ ((idx>>5)&31).
// Makes every exchange phase hit the b64 bank floor (4 lanes/double-bank).
__device__ __forceinline__ int physIdx(int idx) { return idx ^ ((idx >> 5) & 31); }

// DIF digit-reversal (radices 8,8,8,4): bin k lives at this LDS position.
__device__ __forceinline__ int posOf(int k) {
    return ((k & 7) << 8) | (((k >> 3) & 7) << 5) | (((k >> 6) & 7) << 2) | (k >> 9);
}

__device__ __forceinline__ float2 cadd(float2 a, float2 b) { return make_float2(a.x + b.x, a.y + b.y); }
__device__ __forceinline__ float2 csub(float2 a, float2 b) { return make_float2(a.x - b.x, a.y - b.y); }
__device__ __forceinline__ float2 cmulni(float2 a) { return make_float2(a.y, -a.x); }   // * -i
__device__ __forceinline__ float2 cmulpi(float2 a) { return make_float2(-a.y, a.x); }   // * +i
__device__ __forceinline__ float2 cw8(float2 a) {   // * exp(-i*pi/4)
    const float s = 0.70710678118654752f;
    return make_float2(s * (a.x + a.y), s * (a.y - a.x));
}
__device__ __forceinline__ float2 cw83(float2 a) {  // * exp(-i*3pi/4)
    const float s = 0.70710678118654752f;
    return make_float2(s * (a.y - a.x), -s * (a.x + a.y));
}
// * exp(-2*pi*i*m/2048) via 1-ulp HW trig (input in revolutions, m in [0,2048))
__device__ __forceinline__ float2 ctw(float2 a, int m) {
    const float rev = (float)m * (1.0f / 2048.0f);
    const float c = __builtin_amdgcn_cosf(rev);
    const float s = __builtin_amdgcn_sinf(rev);
    return make_float2(a.x * c + a.y * s, a.y * c - a.x * s);
}

// 8-point DFT in registers (DIF core): r[p] <- sum_q r[q] * w8^(p*q)
__device__ __forceinline__ void radix8(float2* r) {
    float2 E0, E1, E2, E3, O0, O1, O2, O3;
    {
        float2 s0 = cadd(r[0], r[4]), s1 = csub(r[0], r[4]);
        float2 s2 = cadd(r[2], r[6]), s3 = csub(r[2], r[6]);
        E0 = cadd(s0, s2); E2 = csub(s0, s2);
        E1 = cadd(s1, cmulni(s3)); E3 = cadd(s1, cmulpi(s3));
    }
    {
        float2 s0 = cadd(r[1], r[5]), s1 = csub(r[1], r[5]);
        float2 s2 = cadd(r[3], r[7]), s3 = csub(r[3], r[7]);
        O0 = cadd(s0, s2); O2 = csub(s0, s2);
        O1 = cadd(s1, cmulni(s3)); O3 = cadd(s1, cmulpi(s3));
    }
    const float2 w1 = cw8(O1), w2 = cmulni(O2), w3 = cw83(O3);
    r[0] = cadd(E0, O0); r[4] = csub(E0, O0);
    r[1] = cadd(E1, w1); r[5] = csub(E1, w1);
    r[2] = cadd(E2, w2); r[6] = csub(E2, w2);
    r[3] = cadd(E3, w3); r[7] = csub(E3, w3);
}

// ---------------------------------------------------------------------------
// Main kernel: packed 2-channel fp32 FFT (radix 8/8/8/4 DIF, 3 LDS exchanges)
// + per-signal one-wave top-12 selection + risk flag for fp64 refinement.
// ---------------------------------------------------------------------------
__global__ __launch_bounds__(256) void fft_topk_kernel(const float* __restrict__ x,
                                                       int* __restrict__ idxw,
                                                       float* __restrict__ rew,
                                                       float* __restrict__ imw,
                                                       int* __restrict__ cand,
                                                       int* __restrict__ flag) {
    __shared__ float2 Z[TT];                       // 16 KB, swizzled
    __shared__ unsigned long long keys[TT];        // 16 KB: [sig*1024 + k]

    // XCD swizzle: all 32 dp-blocks of one batch b on one XCD (L2 line reuse).
    const int i    = blockIdx.x;
    const int xcd  = i & 7;
    const int slot = i >> 3;                       // 0..127
    const int b    = xcd * 4 + (slot >> 5);        // 0..31
    const int dp   = slot & 31;                    // d-pair
    const int t    = threadIdx.x;

    // Load 8 points, stride 256 (phase-1 taps come straight from global).
    const float2* xv = (const float2*)x;
    const size_t base = (size_t)b * TT * (DD / 2) + dp;
    float2 r[8];
    #pragma unroll
    for (int q = 0; q < 8; ++q) r[q] = xv[base + (size_t)(t + 256 * q) * (DD / 2)];

    // Phase 1: L=2048, j=t, taps stride 256
    radix8(r);
    #pragma unroll
    for (int p = 1; p < 8; ++p) r[p] = ctw(r[p], (p * t) & (TT - 1));
    #pragma unroll
    for (int p = 0; p < 8; ++p) Z[physIdx(t + (p << 8))] = r[p];
    __syncthreads();

    // Phase 2: L=256, S=(t>>5)<<8, j=t&31, taps stride 32
    const int S2 = (t >> 5) << 8, j2 = t & 31;
    #pragma unroll
    for (int p = 0; p < 8; ++p) r[p] = Z[physIdx(S2 + j2 + (p << 5))];
    radix8(r);
    #pragma unroll
    for (int p = 1; p < 8; ++p) r[p] = ctw(r[p], (8 * p * j2) & (TT - 1));
    #pragma unroll
    for (int p = 0; p < 8; ++p) Z[physIdx(S2 + j2 + (p << 5))] = r[p];
    __syncthreads();

    // Phase 3: L=32, S=(t>>2)<<5, j=t&3, taps stride 4
    const int S3 = (t >> 2) << 5, j3 = t & 3;
    #pragma unroll
    for (int p = 0; p < 8; ++p) r[p] = Z[physIdx(S3 + j3 + (p << 2))];
    radix8(r);
    #pragma unroll
    for (int p = 1; p < 8; ++p) r[p] = ctw(r[p], (64 * p * j3) & (TT - 1));
    #pragma unroll
    for (int p = 0; p < 8; ++p) Z[physIdx(S3 + j3 + (p << 2))] = r[p];
    __syncthreads();

    // Phase 4: L=4, two final DFT4s on consecutive quads (no twiddles)
    #pragma unroll
    for (int g = 0; g < 2; ++g) {
        const int b4 = 8 * t + 4 * g;
        const float2 a = Z[physIdx(b4)],     bb = Z[physIdx(b4 + 1)];
        const float2 c = Z[physIdx(b4 + 2)], dd = Z[physIdx(b4 + 3)];
        const float2 s0 = cadd(a, c), s1 = csub(a, c);
        const float2 s2 = cadd(bb, dd), s3 = csub(bb, dd);
        Z[physIdx(b4)]     = cadd(s0, s2);
        Z[physIdx(b4 + 1)] = cadd(s1, cmulni(s3));
        Z[physIdx(b4 + 2)] = csub(s0, s2);
        Z[physIdx(b4 + 3)] = cadd(s1, cmulpi(s3));
    }
    __syncthreads();

    // Magnitudes -> packed keys (magbits<<32 | 4095-k : max-key == stable topk)
    if (t < 2) keys[t * 1024] = 0ULL;              // k=0 slots, both signals
    #pragma unroll
    for (int p = 0; p < 4; ++p) {
        const int k = 4 * t + 1 + p;
        if (k <= TT / 2 - 1) {
            const float2 z = Z[physIdx(posOf(k))];
            const float2 y = Z[physIdx(posOf(TT - k))];
            const float x1r = 0.5f * (z.x + y.x), x1i = 0.5f * (z.y - y.y);
            const float x2r = 0.5f * (z.y + y.y), x2i = 0.5f * (y.x - z.x);
            const float m1 = x1r * x1r + x1i * x1i;
            const float m2 = x2r * x2r + x2i * x2i;
            keys[k]        = ((unsigned long long)__float_as_uint(m1) << 32) | (unsigned)(4095 - k);
            keys[1024 + k] = ((unsigned long long)__float_as_uint(m2) << 32) | (unsigned)(4095 - k);
        }
    }
    __syncthreads();

    // One wave per signal: top-12 via 12 shuffle-max passes (no barriers).
    const int wv = t >> 6, lane = t & 63;
    if (wv < 2) {
        const int sig = wv;
        unsigned long long kk[16];
        #pragma unroll
        for (int m = 0; m < 16; ++m) kk[m] = keys[sig * 1024 + lane + 64 * m];
        unsigned long long local = 0;
        #pragma unroll
        for (int m = 0; m < 16; ++m) local = (kk[m] > local) ? kk[m] : local;

        unsigned long long mykey = 0;              // lane r keeps pass-r winner
        for (int pass = 0; pass < NCAND; ++pass) {
            unsigned long long w = local;
            #pragma unroll
            for (int off = 1; off < 64; off <<= 1) {
                const unsigned long long o = __shfl_xor(w, off, 64);
                if (o > w) w = o;
            }
            if (w == local && w != 0ULL) {         // I owned it: invalidate
                #pragma unroll
                for (int m = 0; m < 16; ++m) if (kk[m] == w) kk[m] = 0ULL;
                local = 0;
                #pragma unroll
                for (int m = 0; m < 16; ++m) local = (kk[m] > local) ? kk[m] : local;
            }
            if (lane == pass) mykey = w;
        }

        const unsigned long long k7 = __shfl(mykey, 7, 64);
        const unsigned long long k8 = __shfl(mykey, 8, 64);
        const float m8 = __uint_as_float((unsigned)(k7 >> 32));
        const float m9 = __uint_as_float((unsigned)(k8 >> 32));
        const int s_sig = b * DD + 2 * dp + sig;
        if (lane == 0) flag[s_sig] = (m8 - m9 <= MARGIN * m8) ? 1 : 0;

        const int kwin = 4095 - (int)(mykey & 0xFFFFFFFFULL);
        if (lane < NCAND) cand[s_sig * NCAND + lane] = kwin;
        if (lane < KTOP) {
            const float2 z = Z[physIdx(posOf(kwin))];
            const float2 y = Z[physIdx(posOf(TT - kwin))];
            float cr, ci;
            if (sig == 0) { cr = 0.5f * (z.x + y.x); ci = 0.5f * (z.y - y.y); }
            else          { cr = 0.5f * (z.y + y.y); ci = 0.5f * (y.x - z.x); }
            idxw[s_sig * KTOP + lane] = kwin;
            rew[s_sig * KTOP + lane]  = cr * (2.0f / (float)TT);
            imw[s_sig * KTOP + lane]  = ci * (2.0f / (float)TT);
        }
    }
}

// fp64 twiddle table for the refine kernel: twd[j] = exp(-2*pi*i*j/2048)
__global__ void twiddle64(double2* __restrict__ twd) {
    const int j = blockIdx.x * 256 + threadIdx.x;
    if (j < TT) {
        const double th = -2.0 * PI_D * (double)j / (double)TT;
        twd[j] = make_double2(cos(th), sin(th));
    }
}

// ---------------------------------------------------------------------------
// Refine: for flagged signals only, recompute the 12 candidate bins in fp64
// (Goertzel-style dot) and redo top-8 -> selection identical to full fp64.
// ---------------------------------------------------------------------------
__global__ __launch_bounds__(256) void refine_kernel(const float* __restrict__ x,
                                                     const double2* __restrict__ twd,
                                                     const int* __restrict__ cand,
                                                     const int* __restrict__ flag,
                                                     int* __restrict__ idxw,
                                                     float* __restrict__ rew,
                                                     float* __restrict__ imw) {
    const int s = blockIdx.x;
    if (!flag[s]) return;                          // uniform early-exit

    __shared__ float   xs[TT];                     // 8 KB
    __shared__ double2 tws[TT];                    // 32 KB
    __shared__ double  resR[NCAND], resI[NCAND], resM[NCAND];

    const int b = s >> 6, d = s & 63, t = threadIdx.x;
    for (int n = t; n < TT; n += 256) {
        xs[n]  = x[((size_t)b * TT + n) * DD + d];
        tws[n] = twd[n];
    }
    __syncthreads();

    const int wv = t >> 6, lane = t & 63;
    for (int r = wv; r < NCAND; r += 4) {
        const int k = cand[s * NCAND + r];
        double ar = 0.0, ai = 0.0;
        for (int m = 0; m < TT / 64; ++m) {
            const int n = lane + 64 * m;
            const double2 w = tws[(k * n) & (TT - 1)];
            const double xvn = (double)xs[n];
            ar += xvn * w.x;
            ai += xvn * w.y;
        }
        #pragma unroll
        for (int off = 32; off; off >>= 1) {
            ar += __shfl_xor(ar, off, 64);
            ai += __shfl_xor(ai, off, 64);
        }
        if (lane == 0) { resR[r] = ar; resI[r] = ai; resM[r] = ar * ar + ai * ai; }
    }
    __syncthreads();

    if (t < NCAND) {
        const double m = resM[t];
        const int    k = cand[s * NCAND + t];
        int rank = 0;
        for (int r = 0; r < NCAND; ++r) {
            const double mr = resM[r];
            const int    kr = cand[s * NCAND + r];
            if (mr > m || (mr == m && kr < k)) ++rank;
        }
        if (rank < KTOP) {
            idxw[s * KTOP + rank] = k;
            rew[s * KTOP + rank]  = (float)(resR[t] * (2.0 / (double)TT));
            imw[s * KTOP + rank]  = (float)(resI[t] * (2.0 / (double)TT));
        }
    }
}

// ---------------------------------------------------------------------------
// Synthesis (unchanged from R1, verified): d-major lanes, coalesced stores,
// exact integer angle reduction + HW trig.
// ---------------------------------------------------------------------------
__global__ __launch_bounds__(256) void synth_kernel(const int* __restrict__ idxw,
                                                    const float* __restrict__ rew,
                                                    const float* __restrict__ imw,
                                                    float* __restrict__ out) {
    const int NT   = (TP + 127) / 128;   // 17 tiles
    const int b    = blockIdx.x / NT;
    const int tile = blockIdx.x % NT;
    const int tid  = threadIdx.x;
    const int d    = tid & 63;
    const int tq   = tid >> 6;
    const int s    = b * DD + d;

    int   kk[KTOP];
    float rr[KTOP], ii[KTOP];
    int   jj[KTOP];
    #pragma unroll
    for (int p = 0; p < KTOP; ++p) {
        kk[p] = idxw[s * KTOP + p];
        rr[p] = rew[s * KTOP + p];
        ii[p] = imw[s * KTOP + p];
    }
    const int t0 = tile * 128 + tq * 32;
    #pragma unroll
    for (int p = 0; p < KTOP; ++p) jj[p] = (kk[p] * t0) & (TT - 1);

    const float invT = 1.0f / (float)TT;
    for (int i = 0; i < 32; ++i) {
        const int t = t0 + i;
        if (t < TP) {
            float acc = 0.0f;
            #pragma unroll
            for (int p = 0; p < KTOP; ++p) {
                const float rev = (float)jj[p] * invT;
                const float c  = __builtin_amdgcn_cosf(rev);
                const float sn = __builtin_amdgcn_sinf(rev);
                acc += rr[p] * c - ii[p] * sn;
            }
            out[((size_t)b * TP + t) * DD + d] = acc;
        }
        #pragma unroll
        for (int p = 0; p < KTOP; ++p) jj[p] = (jj[p] + kk[p]) & (TT - 1);
    }
}

extern "C" void kernel_launch(void* const* d_in, const int* in_sizes, int n_in,
                              void* d_out, int out_size, void* d_ws, size_t ws_size,
                              hipStream_t stream) {
    const float* x = (const float*)d_in[0];
    float* out = (float*)d_out;

    // ws: twd double2[2048] | idxw | rew | imw | cand | flag
    double2* twd = (double2*)d_ws;
    char* p = (char*)d_ws + (size_t)TT * sizeof(double2);
    int*   idxw = (int*)p;                 p += (size_t)NSIG * KTOP * sizeof(int);
    float* rew  = (float*)p;               p += (size_t)NSIG * KTOP * sizeof(float);
    float* imw  = (float*)p;               p += (size_t)NSIG * KTOP * sizeof(float);
    int*   cand = (int*)p;                 p += (size_t)NSIG * NCAND * sizeof(int);
    int*   flag = (int*)p;

    twiddle64<<<(TT + 255) / 256, 256, 0, stream>>>(twd);
    fft_topk_kernel<<<NSIG / 2, 256, 0, stream>>>(x, idxw, rew, imw, cand, flag);
    refine_kernel<<<NSIG, 256, 0, stream>>>(x, twd, cand, flag, idxw, rew, imw);

    const int NT = (TP + 127) / 128;
    synth_kernel<<<BB * NT, 256, 0, stream>>>(idxw, rew, imw, out);
}

// Round 4
// 113.227 us; speedup vs baseline: 13.3559x; 1.0734x over previous
//
#include <hip/hip_runtime.h>
#include <math.h>

#define BB 32
#define TT 2048
#define DD 64
#define PRED 96
#define TP (TT + PRED)      // 2144
#define KTOP 8
#define NCAND 12
#define NSIG (BB * DD)      // 2048
#define MARGIN 2e-4f
#define PI_D 3.14159265358979323846

// LDS bank swizzle for the float2 FFT array: phys = idx ^ ((idx>>5)&31).
__device__ __forceinline__ int physIdx(int idx) { return idx ^ ((idx >> 5) & 31); }

// DIF digit-reversal (radices 8,8,8,4): bin k lives at this LDS position.
__device__ __forceinline__ int posOf(int k) {
    return ((k & 7) << 8) | (((k >> 3) & 7) << 5) | (((k >> 6) & 7) << 2) | (k >> 9);
}

__device__ __forceinline__ float2 cadd(float2 a, float2 b) { return make_float2(a.x + b.x, a.y + b.y); }
__device__ __forceinline__ float2 csub(float2 a, float2 b) { return make_float2(a.x - b.x, a.y - b.y); }
__device__ __forceinline__ float2 cmulni(float2 a) { return make_float2(a.y, -a.x); }   // * -i
__device__ __forceinline__ float2 cmulpi(float2 a) { return make_float2(-a.y, a.x); }   // * +i
__device__ __forceinline__ float2 cw8(float2 a) {   // * exp(-i*pi/4)
    const float s = 0.70710678118654752f;
    return make_float2(s * (a.x + a.y), s * (a.y - a.x));
}
__device__ __forceinline__ float2 cw83(float2 a) {  // * exp(-i*3pi/4)
    const float s = 0.70710678118654752f;
    return make_float2(s * (a.y - a.x), -s * (a.x + a.y));
}
// * exp(-2*pi*i*m/2048) via 1-ulp HW trig (input in revolutions)
__device__ __forceinline__ float2 ctw(float2 a, int m) {
    const float rev = (float)m * (1.0f / 2048.0f);
    const float c = __builtin_amdgcn_cosf(rev);
    const float s = __builtin_amdgcn_sinf(rev);
    return make_float2(a.x * c + a.y * s, a.y * c - a.x * s);
}

// 8-point DFT in registers (DIF core)
__device__ __forceinline__ void radix8(float2* r) {
    float2 E0, E1, E2, E3, O0, O1, O2, O3;
    {
        float2 s0 = cadd(r[0], r[4]), s1 = csub(r[0], r[4]);
        float2 s2 = cadd(r[2], r[6]), s3 = csub(r[2], r[6]);
        E0 = cadd(s0, s2); E2 = csub(s0, s2);
        E1 = cadd(s1, cmulni(s3)); E3 = cadd(s1, cmulpi(s3));
    }
    {
        float2 s0 = cadd(r[1], r[5]), s1 = csub(r[1], r[5]);
        float2 s2 = cadd(r[3], r[7]), s3 = csub(r[3], r[7]);
        O0 = cadd(s0, s2); O2 = csub(s0, s2);
        O1 = cadd(s1, cmulni(s3)); O3 = cadd(s1, cmulpi(s3));
    }
    const float2 w1 = cw8(O1), w2 = cmulni(O2), w3 = cw83(O3);
    r[0] = cadd(E0, O0); r[4] = csub(E0, O0);
    r[1] = cadd(E1, w1); r[5] = csub(E1, w1);
    r[2] = cadd(E2, w2); r[6] = csub(E2, w2);
    r[3] = cadd(E3, w3); r[7] = csub(E3, w3);
}

// ---------------------------------------------------------------------------
// Fused kernel: fp32 radix-8/8/8/4 FFT (2 packed real channels) + one-wave
// top-12 selection + in-block fp64 refine for risk-flagged signals.
// ---------------------------------------------------------------------------
__global__ __launch_bounds__(256) void fft_topk_kernel(const float* __restrict__ x,
                                                       int* __restrict__ idxw,
                                                       float* __restrict__ rew,
                                                       float* __restrict__ imw) {
    __shared__ float2 Z[TT];                       // 16 KB, swizzled
    __shared__ unsigned long long keys[TT];        // 16 KB; reused as xs2 in refine
    __shared__ int    candS[2][NCAND];
    __shared__ int    flagS[2];
    __shared__ double resR[2][NCAND], resI[2][NCAND], resM[2][NCAND];
    __shared__ double2 wA[32];                     // exp(-i*pi*q/16)
    __shared__ double2 wB[64];                     // exp(-2*pi*i*j/2048)

    // XCD swizzle: all 32 dp-blocks of one batch b on one XCD.
    const int i    = blockIdx.x;
    const int xcd  = i & 7;
    const int slot = i >> 3;
    const int b    = xcd * 4 + (slot >> 5);
    const int dp   = slot & 31;
    const int t    = threadIdx.x;

    const float2* xv = (const float2*)x;
    const size_t base = (size_t)b * TT * (DD / 2) + dp;
    float2 r[8];
    #pragma unroll
    for (int q = 0; q < 8; ++q) r[q] = xv[base + (size_t)(t + 256 * q) * (DD / 2)];

    // Phase 1: L=2048
    radix8(r);
    #pragma unroll
    for (int p = 1; p < 8; ++p) r[p] = ctw(r[p], (p * t) & (TT - 1));
    #pragma unroll
    for (int p = 0; p < 8; ++p) Z[physIdx(t + (p << 8))] = r[p];
    __syncthreads();

    // Phase 2: L=256
    const int S2 = (t >> 5) << 8, j2 = t & 31;
    #pragma unroll
    for (int p = 0; p < 8; ++p) r[p] = Z[physIdx(S2 + j2 + (p << 5))];
    radix8(r);
    #pragma unroll
    for (int p = 1; p < 8; ++p) r[p] = ctw(r[p], (8 * p * j2) & (TT - 1));
    #pragma unroll
    for (int p = 0; p < 8; ++p) Z[physIdx(S2 + j2 + (p << 5))] = r[p];
    __syncthreads();

    // Phase 3: L=32
    const int S3 = (t >> 2) << 5, j3 = t & 3;
    #pragma unroll
    for (int p = 0; p < 8; ++p) r[p] = Z[physIdx(S3 + j3 + (p << 2))];
    radix8(r);
    #pragma unroll
    for (int p = 1; p < 8; ++p) r[p] = ctw(r[p], (64 * p * j3) & (TT - 1));
    #pragma unroll
    for (int p = 0; p < 8; ++p) Z[physIdx(S3 + j3 + (p << 2))] = r[p];
    __syncthreads();

    // Phase 4: two final DFT4s on consecutive quads
    #pragma unroll
    for (int g = 0; g < 2; ++g) {
        const int b4 = 8 * t + 4 * g;
        const float2 a = Z[physIdx(b4)],     bb = Z[physIdx(b4 + 1)];
        const float2 c = Z[physIdx(b4 + 2)], dd = Z[physIdx(b4 + 3)];
        const float2 s0 = cadd(a, c), s1 = csub(a, c);
        const float2 s2 = cadd(bb, dd), s3 = csub(bb, dd);
        Z[physIdx(b4)]     = cadd(s0, s2);
        Z[physIdx(b4 + 1)] = cadd(s1, cmulni(s3));
        Z[physIdx(b4 + 2)] = csub(s0, s2);
        Z[physIdx(b4 + 3)] = cadd(s1, cmulpi(s3));
    }
    __syncthreads();

    // Magnitudes -> keys (magbits<<32 | 4095-k: u64 max == stable top-k)
    if (t < 2) keys[t * 1024] = 0ULL;              // k=0 excluded
    #pragma unroll
    for (int p = 0; p < 4; ++p) {
        const int k = 4 * t + 1 + p;
        if (k <= TT / 2 - 1) {
            const float2 z = Z[physIdx(posOf(k))];
            const float2 y = Z[physIdx(posOf(TT - k))];
            const float x1r = 0.5f * (z.x + y.x), x1i = 0.5f * (z.y - y.y);
            const float x2r = 0.5f * (z.y + y.y), x2i = 0.5f * (y.x - z.x);
            const float m1 = x1r * x1r + x1i * x1i;
            const float m2 = x2r * x2r + x2i * x2i;
            keys[k]        = ((unsigned long long)__float_as_uint(m1) << 32) | (unsigned)(4095 - k);
            keys[1024 + k] = ((unsigned long long)__float_as_uint(m2) << 32) | (unsigned)(4095 - k);
        }
    }
    __syncthreads();

    // One wave per signal: top-12 via shuffle-max passes (no barriers).
    const int wv = t >> 6, lane = t & 63;
    if (wv < 2) {
        const int sig = wv;
        unsigned long long kk[16];
        #pragma unroll
        for (int m = 0; m < 16; ++m) kk[m] = keys[sig * 1024 + lane + 64 * m];
        unsigned long long local = 0;
        #pragma unroll
        for (int m = 0; m < 16; ++m) local = (kk[m] > local) ? kk[m] : local;

        unsigned long long mykey = 0;              // lane r keeps pass-r winner
        for (int pass = 0; pass < NCAND; ++pass) {
            unsigned long long w = local;
            #pragma unroll
            for (int off = 1; off < 64; off <<= 1) {
                const unsigned long long o = __shfl_xor(w, off, 64);
                if (o > w) w = o;
            }
            if (w == local && w != 0ULL) {         // owner invalidates
                #pragma unroll
                for (int m = 0; m < 16; ++m) if (kk[m] == w) kk[m] = 0ULL;
                local = 0;
                #pragma unroll
                for (int m = 0; m < 16; ++m) local = (kk[m] > local) ? kk[m] : local;
            }
            if (lane == pass) mykey = w;
        }

        const unsigned long long k7 = __shfl(mykey, 7, 64);
        const unsigned long long k8 = __shfl(mykey, 8, 64);
        const float m8 = __uint_as_float((unsigned)(k7 >> 32));
        const float m9 = __uint_as_float((unsigned)(k8 >> 32));
        const int flg = (m8 - m9 <= MARGIN * m8) ? 1 : 0;   // uniform across wave
        if (lane == 0) flagS[sig] = flg;

        const int kwin = 4095 - (int)(mykey & 0xFFFFFFFFULL);
        if (lane < NCAND) candS[sig][lane] = kwin;
        if (!flg && lane < KTOP) {
            const float2 z = Z[physIdx(posOf(kwin))];
            const float2 y = Z[physIdx(posOf(TT - kwin))];
            float cr, ci;
            if (sig == 0) { cr = 0.5f * (z.x + y.x); ci = 0.5f * (z.y - y.y); }
            else          { cr = 0.5f * (z.y + y.y); ci = 0.5f * (y.x - z.x); }
            const int s_sig = b * DD + 2 * dp + sig;
            idxw[s_sig * KTOP + lane] = kwin;
            rew[s_sig * KTOP + lane]  = cr * (2.0f / (float)TT);
            imw[s_sig * KTOP + lane]  = ci * (2.0f / (float)TT);
        }
    }
    __syncthreads();

    // ---- In-block fp64 refine (rare path, ~1% of blocks) ----
    if (flagS[0] | flagS[1]) {
        float2* xs2 = (float2*)keys;               // reuse keys region (16 KB)
        #pragma unroll
        for (int q = 0; q < 8; ++q)
            xs2[t + 256 * q] = xv[base + (size_t)(t + 256 * q) * (DD / 2)];
        // fp64 twiddle factor tables: tw(m) = wA[m>>6] * wB[m&63]
        if (t < 32) {
            const double th = -PI_D * (double)t / 16.0;
            wA[t] = make_double2(cos(th), sin(th));
        } else if (t < 96) {
            const int j = t - 32;
            const double th = -2.0 * PI_D * (double)j / (double)TT;
            wB[j] = make_double2(cos(th), sin(th));
        }
        __syncthreads();

        for (int sig = 0; sig < 2; ++sig) {
            if (!flagS[sig]) continue;
            for (int rr = wv; rr < NCAND; rr += 4) {
                const int k = candS[sig][rr];
                double ar = 0.0, ai = 0.0;
                for (int m = 0; m < TT / 64; ++m) {
                    const int n   = lane + 64 * m;
                    const int ix  = (k * n) & (TT - 1);
                    const double2 a  = wA[ix >> 6];
                    const double2 bw = wB[ix & 63];
                    const double wr = a.x * bw.x - a.y * bw.y;
                    const double wi = a.x * bw.y + a.y * bw.x;
                    const double xn = (sig == 0) ? (double)xs2[n].x : (double)xs2[n].y;
                    ar = fma(xn, wr, ar);
                    ai = fma(xn, wi, ai);
                }
                #pragma unroll
                for (int off = 32; off; off >>= 1) {
                    ar += __shfl_xor(ar, off, 64);
                    ai += __shfl_xor(ai, off, 64);
                }
                if (lane == 0) {
                    resR[sig][rr] = ar; resI[sig][rr] = ai;
                    resM[sig][rr] = ar * ar + ai * ai;
                }
            }
        }
        __syncthreads();

        if (t < 2 * NCAND) {
            const int sig = t / NCAND, rr = t % NCAND;
            if (flagS[sig]) {
                const double m = resM[sig][rr];
                const int    k = candS[sig][rr];
                int rank = 0;
                for (int r2 = 0; r2 < NCAND; ++r2) {
                    const double m2 = resM[sig][r2];
                    const int    k2 = candS[sig][r2];
                    if (m2 > m || (m2 == m && k2 < k)) ++rank;
                }
                if (rank < KTOP) {
                    const int s_sig = b * DD + 2 * dp + sig;
                    idxw[s_sig * KTOP + rank] = k;
                    rew[s_sig * KTOP + rank]  = (float)(resR[sig][rr] * (2.0 / (double)TT));
                    imw[s_sig * KTOP + rank]  = (float)(resI[sig][rr] * (2.0 / (double)TT));
                }
            }
        }
    }
}

// ---------------------------------------------------------------------------
// Synthesis (verified): d-major lanes, coalesced stores, exact integer angle
// reduction + HW trig.
// ---------------------------------------------------------------------------
__global__ __launch_bounds__(256) void synth_kernel(const int* __restrict__ idxw,
                                                    const float* __restrict__ rew,
                                                    const float* __restrict__ imw,
                                                    float* __restrict__ out) {
    const int NT   = (TP + 127) / 128;   // 17 tiles
    const int b    = blockIdx.x / NT;
    const int tile = blockIdx.x % NT;
    const int tid  = threadIdx.x;
    const int d    = tid & 63;
    const int tq   = tid >> 6;
    const int s    = b * DD + d;

    int   kk[KTOP];
    float rr[KTOP], ii[KTOP];
    int   jj[KTOP];
    #pragma unroll
    for (int p = 0; p < KTOP; ++p) {
        kk[p] = idxw[s * KTOP + p];
        rr[p] = rew[s * KTOP + p];
        ii[p] = imw[s * KTOP + p];
    }
    const int t0 = tile * 128 + tq * 32;
    #pragma unroll
    for (int p = 0; p < KTOP; ++p) jj[p] = (kk[p] * t0) & (TT - 1);

    const float invT = 1.0f / (float)TT;
    for (int i = 0; i < 32; ++i) {
        const int t = t0 + i;
        if (t < TP) {
            float acc = 0.0f;
            #pragma unroll
            for (int p = 0; p < KTOP; ++p) {
                const float rev = (float)jj[p] * invT;
                const float c  = __builtin_amdgcn_cosf(rev);
                const float sn = __builtin_amdgcn_sinf(rev);
                acc += rr[p] * c - ii[p] * sn;
            }
            out[((size_t)b * TP + t) * DD + d] = acc;
        }
        #pragma unroll
        for (int p = 0; p < KTOP; ++p) jj[p] = (jj[p] + kk[p]) & (TT - 1);
    }
}

extern "C" void kernel_launch(void* const* d_in, const int* in_sizes, int n_in,
                              void* d_out, int out_size, void* d_ws, size_t ws_size,
                              hipStream_t stream) {
    const float* x = (const float*)d_in[0];
    float* out = (float*)d_out;

    // ws: idxw | rew | imw
    char* p = (char*)d_ws;
    int*   idxw = (int*)p;     p += (size_t)NSIG * KTOP * sizeof(int);
    float* rew  = (float*)p;   p += (size_t)NSIG * KTOP * sizeof(float);
    float* imw  = (float*)p;

    fft_topk_kernel<<<NSIG / 2, 256, 0, stream>>>(x, idxw, rew, imw);

    const int NT = (TP + 127) / 128;
    synth_kernel<<<BB * NT, 256, 0, stream>>>(idxw, rew, imw, out);
}